// Round 14
// baseline (4300.346 us; speedup 1.0000x reference)
//
#include <hip/hip_runtime.h>
#include <math.h>

// ---------------- problem constants ----------------
#define NB    8
#define NPTS  100000
#define NCLS  18
#define ND    128
#define KFPS  2048
#define KTOP  256

// ---------------- FPS config ----------------
#define FWGS       32                 // workgroups per batch
#define FTHR       256                // threads per WG
#define FBTHREADS  (FWGS*FTHR)        // 8192 threads per batch
#define PPT        13                 // points per thread (13*8192 >= 100000)
#define NSLOT      32                 // one slot (4 records) per WG per batch
#define RSTRIDE    64                 // u64s per slot (512 B) -> MALL slice spread
#define TAG_SHIFT  49
#define KEY_MASK   ((1ull<<TAG_SHIFT)-1)
#define IDX_MASK   0x1FFFFull
#define INVALID_REC (~0ull)           // tag 0x7FFF: never matches live tags

// per-batch u64 region: 2 banks x 32 slots x 64 u64-stride (slot holds 4 recs)
#define BANK_U64   (NSLOT * RSTRIDE)            // 2048
#define B_TOTAL    (2 * BANK_U64)               // 4096
#define PART_U64   (NB * B_TOTAL)               // 32768 u64 = 256 KB

static_assert(PPT * FBTHREADS >= NPTS, "coverage");

// ---------------- out layout (float elements), total 2367488 ----------------
#define OUT_PTS    0          // 8*256*3    = 6144
#define OUT_FEATS  6144       // 8*256*128  = 262144
#define OUT_INDS   268288     // 8*256      = 2048
#define OUT_CROSS  270336     // 8*2048*128 = 2097152
// scratch INSIDE region 3 (overwritten by k_gather at the end):
#define OUT_SCORES OUT_CROSS              // 800000 floats
#define OUT_PART   (OUT_CROSS + 800000)   // 8B-aligned
static_assert((OUT_PART % 2) == 0, "u64 alignment");
static_assert(OUT_PART + PART_U64 * 2 <= OUT_CROSS + 2097152, "fits in region 3");

// ---------------- ws layout (bytes) — proven-safe 90112 ----------------
#define WS_CROSS    16384                   // NB*KFPS*4 = 65536
#define WS_SORTI    (16384+65536)           // NB*KTOP*4 = 8192   (end 90112)

// ============================================================
// Kernel 0: init record slots (runs before k_fps every call)
// ============================================================
__global__ void k_init(unsigned long long* __restrict__ partials) {
  int id = blockIdx.x * 256 + threadIdx.x;
  if (id < PART_U64)
    __hip_atomic_store(&partials[id], INVALID_REC,
                       __ATOMIC_RELAXED, __HIP_MEMORY_SCOPE_AGENT);
}

// ============================================================
// Kernel 1: max_scores = sigmoid(max_c cls) * sigmoid(centerness)
// ============================================================
__global__ void k_scores(const float* __restrict__ cent,
                         const float* __restrict__ cls,
                         float* __restrict__ scores) {
  int gid = blockIdx.x * blockDim.x + threadIdx.x;
  if (gid >= NB * NPTS) return;
  const float* c = cls + (size_t)gid * NCLS;
  float m = c[0];
  #pragma unroll
  for (int i = 1; i < NCLS; ++i) m = fmaxf(m, c[i]);
  double sm = 1.0 / (1.0 + exp(-(double)m));
  double sc = 1.0 / (1.0 + exp(-(double)cent[gid]));
  scores[gid] = __fmul_rn((float)sm, (float)sc);
}

// ============================================================
// Kernel 2: per-batch exact top-256 (value desc, idx asc), output sorted idx
// ============================================================
__global__ __launch_bounds__(1024) void k_topk(const float* __restrict__ scores,
                                               int* __restrict__ sorti_ws,
                                               float* __restrict__ out_inds) {
  __shared__ unsigned hist[2048];
  __shared__ int candG[256];
  __shared__ int candE[512];
  __shared__ unsigned s_cg, s_ce, s_bin, s_rank;

  int b = blockIdx.x;
  int tid = threadIdx.x;
  const float* sb = scores + (size_t)b * NPTS;

  unsigned prefix = 0, pmask = 0;
  int r = KTOP;
  for (int pass = 0; pass < 3; ++pass) {
    int shift = (pass == 0) ? 21 : (pass == 1) ? 10 : 0;
    int bins  = (pass < 2) ? 2048 : 1024;
    for (int i = tid; i < bins; i += 1024) hist[i] = 0;
    __syncthreads();
    for (int n = tid; n < NPTS; n += 1024) {
      unsigned k = __float_as_uint(sb[n]);
      if ((k & pmask) == prefix) atomicAdd(&hist[(k >> shift) & (bins - 1)], 1u);
    }
    __syncthreads();
    if (tid == 0) {
      unsigned c = 0; int bin = bins - 1;
      for (; bin > 0; --bin) { unsigned h = hist[bin]; if (c + h >= (unsigned)r) break; c += h; }
      s_bin = (unsigned)bin; s_rank = (unsigned)r - c;
    }
    __syncthreads();
    prefix |= s_bin << shift;
    pmask  |= (unsigned)(bins - 1) << shift;
    r = (int)s_rank;
    __syncthreads();
  }
  unsigned T = prefix;
  int need = r;
  int nG = KTOP - need;

  if (tid == 0) { s_cg = 0; s_ce = 0; }
  __syncthreads();
  for (int n = tid; n < NPTS; n += 1024) {
    unsigned k = __float_as_uint(sb[n]);
    if (k > T)       { unsigned p = atomicAdd(&s_cg, 1u); if (p < 256) candG[p] = n; }
    else if (k == T) { unsigned p = atomicAdd(&s_ce, 1u); if (p < 512) candE[p] = n; }
  }
  __syncthreads();
  unsigned ce = s_ce;
  for (int i = tid; i < 512; i += 1024) if (i >= (int)ce) candE[i] = 0x7FFFFFFF;
  __syncthreads();
  for (int k2 = 2; k2 <= 512; k2 <<= 1)
    for (int j = k2 >> 1; j >= 1; j >>= 1) {
      if (tid < 512) {
        int i = tid, p = i ^ j;
        if (p > i) {
          int a = candE[i], bb = candE[p];
          bool up = ((i & k2) == 0);
          if ((a > bb) == up) { candE[i] = bb; candE[p] = a; }
        }
      }
      __syncthreads();
    }
  int* arr = (int*)hist;
  if (tid < KTOP) arr[tid] = (tid < nG) ? candG[tid] : candE[tid - nG];
  __syncthreads();
  for (int k2 = 2; k2 <= 256; k2 <<= 1)
    for (int j = k2 >> 1; j >= 1; j >>= 1) {
      if (tid < 256) {
        int i = tid, p = i ^ j;
        if (p > i) {
          int a = arr[i], bb = arr[p];
          bool up = ((i & k2) == 0);
          if ((a > bb) == up) { arr[i] = bb; arr[p] = a; }
        }
      }
      __syncthreads();
    }
  if (tid < KTOP) {
    sorti_ws[b * KTOP + tid] = arr[tid];
    out_inds[b * KTOP + tid] = (float)arr[tid];
  }
}

// ---- compare-exchange (keep x >= y) and top-4 merge of two desc lists ----
__device__ __forceinline__ void ce_u64(unsigned long long& x, unsigned long long& y) {
  unsigned long long mx = (x > y) ? x : y;
  unsigned long long mn = (x > y) ? y : x;
  x = mx; y = mn;
}
__device__ __forceinline__ void merge4(unsigned long long& a1, unsigned long long& a2,
                                       unsigned long long& a3, unsigned long long& a4,
                                       unsigned long long b1, unsigned long long b2,
                                       unsigned long long b3, unsigned long long b4) {
  unsigned long long t1 = (a1 > b4) ? a1 : b4;
  unsigned long long t2 = (a2 > b3) ? a2 : b3;
  unsigned long long t3 = (a3 > b2) ? a3 : b2;
  unsigned long long t4 = (a4 > b1) ? a4 : b1;
  ce_u64(t1, t3); ce_u64(t2, t4); ce_u64(t1, t2); ce_u64(t3, t4);
  a1 = t1; a2 = t2; a3 = t3; a4 = t4;
}

// ============================================================
// Kernel 3: FPS with exact top-4 lookahead chain.
// Per consensus: per-thread top-4 -> wave butterfly merge4 -> per-WG
// top-4 published as 4 tagged records/slot -> r11-proven poll -> global
// merge4 -> candidate list (g1..g4). Emit idx1; chain-validate idx_j
// (v_j>0 && d2(p_j,e_m)>=v_j for all m<j, bit-exact, uniform) to emit
// up to 4 per consensus; fold pass per accepted emission (r13-proven).
// Tag = consensus counter + 1; ping-pong banks by counter parity.
// Bounded spins, heal-stores, clamped indices.
// ============================================================
__global__ __launch_bounds__(FTHR, 1) void k_fps(const float* __restrict__ points,
                                                 unsigned long long* __restrict__ partials,
                                                 int* __restrict__ cross_inds) {
  int b    = blockIdx.x & 7;
  int wg   = blockIdx.x >> 3;    // 0..31
  int tid  = threadIdx.x;
  int lane = tid & 63;
  int wave = tid >> 6;           // 0..3
  int gthr = wg * FTHR + tid;

  __shared__ unsigned long long lred[4][4];
  __shared__ unsigned long long lg[4];

  const float* pb = points + (size_t)b * NPTS * 3;
  unsigned long long* base = partials + (size_t)b * B_TOTAL;

  float px[PPT], py[PPT], pz[PPT], dd[PPT];
  #pragma unroll
  for (int i = 0; i < PPT; ++i) {
    int n = gthr + i * FBTHREADS;
    bool v = (n < NPTS);
    px[i] = v ? pb[3 * n + 0] : 0.f;
    py[i] = v ? pb[3 * n + 1] : 0.f;
    pz[i] = v ? pb[3 * n + 2] : 0.f;
    dd[i] = 1e10f;
  }
  if (wg == 0 && tid == 0) cross_inds[b * KFPS] = 0;

  // fold a point's distances into dd (pure min pass, no top-k)
  #define FOLD(fx, fy, fz) do {                                               \
    _Pragma("unroll")                                                         \
    for (int i_ = 0; i_ < PPT; ++i_) {                                        \
      float dx_ = __fsub_rn(px[i_], (fx));                                    \
      float dy_ = __fsub_rn(py[i_], (fy));                                    \
      float dz_ = __fsub_rn(pz[i_], (fz));                                    \
      float s_  = __fadd_rn(__fadd_rn(__fmul_rn(dx_, dx_), __fmul_rn(dy_, dy_)), \
                            __fmul_rn(dz_, dz_));                             \
      dd[i_] = fminf(dd[i_], s_);                                             \
    }                                                                         \
  } while (0)

  int w = 0;          // emitted, to fold at next update pass
  int t = 1;          // next emission slot
  int c = 0;          // consensus counter
  while (t < KFPS) {
    float wx = pb[3 * w + 0];
    float wy = pb[3 * w + 1];
    float wz = pb[3 * w + 2];

    // update pass + per-thread top-4 (packed (val,~idx) keys, desc s1..s4)
    unsigned long long s1 = 0ull, s2 = 0ull, s3 = 0ull, s4 = 0ull;
    #pragma unroll
    for (int i = 0; i < PPT; ++i) {
      int n = gthr + i * FBTHREADS;
      float dx = __fsub_rn(px[i], wx);
      float dy = __fsub_rn(py[i], wy);
      float dz = __fsub_rn(pz[i], wz);
      float s  = __fadd_rn(__fadd_rn(__fmul_rn(dx, dx), __fmul_rn(dy, dy)), __fmul_rn(dz, dz));
      float nd = fminf(dd[i], s);
      dd[i] = nd;
      if (n < NPTS) {
        unsigned long long k = ((unsigned long long)__float_as_uint(nd) << 17) |
                               (unsigned long long)(0x1FFFFu ^ (unsigned)n);
        s4 = (k > s4) ? k : s4;
        ce_u64(s3, s4); ce_u64(s2, s3); ce_u64(s1, s2);
      }
    }
    // wave butterfly top-4
    #pragma unroll
    for (int off = 32; off >= 1; off >>= 1) {
      unsigned long long o1 = __shfl_xor(s1, off);
      unsigned long long o2 = __shfl_xor(s2, off);
      unsigned long long o3 = __shfl_xor(s3, off);
      unsigned long long o4 = __shfl_xor(s4, off);
      merge4(s1, s2, s3, s4, o1, o2, o3, o4);
    }
    if (lane == 0) { lred[wave][0] = s1; lred[wave][1] = s2;
                     lred[wave][2] = s3; lred[wave][3] = s4; }
    __syncthreads();                       // B1

    unsigned tag = (unsigned)c + 1u;
    unsigned long long* bank = base + (size_t)(c & 1) * BANK_U64;
    if (wave == 0) {
      unsigned long long rc[4] = {0, 0, 0, 0};
      if (lane == 0) {
        unsigned long long m1 = lred[0][0], m2 = lred[0][1],
                           m3 = lred[0][2], m4 = lred[0][3];
        merge4(m1, m2, m3, m4, lred[1][0], lred[1][1], lred[1][2], lred[1][3]);
        merge4(m1, m2, m3, m4, lred[2][0], lred[2][1], lred[2][2], lred[2][3]);
        merge4(m1, m2, m3, m4, lred[3][0], lred[3][1], lred[3][2], lred[3][3]);
        rc[0] = ((unsigned long long)tag << TAG_SHIFT) | m1;
        rc[1] = ((unsigned long long)tag << TAG_SHIFT) | m2;
        rc[2] = ((unsigned long long)tag << TAG_SHIFT) | m3;
        rc[3] = ((unsigned long long)tag << TAG_SHIFT) | m4;
        #pragma unroll
        for (int q = 0; q < 4; ++q)
          __hip_atomic_store(&bank[(size_t)wg * RSTRIDE + q], rc[q],
                             __ATOMIC_RELAXED, __HIP_MEMORY_SCOPE_AGENT);
      }
      // r11-proven poll loop over 4-record slots
      unsigned long long r1 = 0, r2 = 0, r3 = 0, r4 = 0;
      unsigned long long* a0 = &bank[(size_t)(lane & 31) * RSTRIDE];
      int spins = 0;
      for (;;) {
        if (lane < 32) {
          r1 = __hip_atomic_load(a0 + 0, __ATOMIC_RELAXED, __HIP_MEMORY_SCOPE_AGENT);
          r2 = __hip_atomic_load(a0 + 1, __ATOMIC_RELAXED, __HIP_MEMORY_SCOPE_AGENT);
          r3 = __hip_atomic_load(a0 + 2, __ATOMIC_RELAXED, __HIP_MEMORY_SCOPE_AGENT);
          r4 = __hip_atomic_load(a0 + 3, __ATOMIC_RELAXED, __HIP_MEMORY_SCOPE_AGENT);
        }
        bool ok = (lane >= 32) ||
                  (((unsigned)(r1 >> TAG_SHIFT) == tag) &&
                   ((unsigned)(r2 >> TAG_SHIFT) == tag) &&
                   ((unsigned)(r3 >> TAG_SHIFT) == tag) &&
                   ((unsigned)(r4 >> TAG_SHIFT) == tag));
        if (__all((int)ok)) break;
        ++spins;
        if (spins > (1 << 11)) break;        // bounded: clamped result, never hangs
        if ((spins & 255) == 0 && lane == 0) {  // heal lost stores
          #pragma unroll
          for (int q = 0; q < 4; ++q)
            __hip_atomic_store(&bank[(size_t)wg * RSTRIDE + q], rc[q],
                               __ATOMIC_RELAXED, __HIP_MEMORY_SCOPE_AGENT);
        }
        if (spins > 512) __builtin_amdgcn_s_sleep(1);
      }
      unsigned long long k1 = (lane < 32) ? (r1 & KEY_MASK) : 0ull;
      unsigned long long k2 = (lane < 32) ? (r2 & KEY_MASK) : 0ull;
      unsigned long long k3 = (lane < 32) ? (r3 & KEY_MASK) : 0ull;
      unsigned long long k4 = (lane < 32) ? (r4 & KEY_MASK) : 0ull;
      #pragma unroll
      for (int off = 32; off >= 1; off >>= 1) {
        unsigned long long o1 = __shfl_xor(k1, off);
        unsigned long long o2 = __shfl_xor(k2, off);
        unsigned long long o3 = __shfl_xor(k3, off);
        unsigned long long o4 = __shfl_xor(k4, off);
        merge4(k1, k2, k3, k4, o1, o2, o3, o4);
      }
      if (lane == 0) { lg[0] = k1; lg[1] = k2; lg[2] = k3; lg[3] = k4; }
    }
    __syncthreads();                       // B2
    unsigned long long g1 = lg[0], g2 = lg[1], g3 = lg[2], g4 = lg[3];
    ++c;

    int i1 = (int)(0x1FFFFu ^ (unsigned)(g1 & IDX_MASK));
    int i2 = (int)(0x1FFFFu ^ (unsigned)(g2 & IDX_MASK));
    int i3 = (int)(0x1FFFFu ^ (unsigned)(g3 & IDX_MASK));
    int i4 = (int)(0x1FFFFu ^ (unsigned)(g4 & IDX_MASK));
    if (i1 >= NPTS) i1 = 0;                // safety: never OOB
    if (i2 >= NPTS) i2 = 0;
    if (i3 >= NPTS) i3 = 0;
    if (i4 >= NPTS) i4 = 0;
    float v2 = __uint_as_float((unsigned)(g2 >> 17));
    float v3 = __uint_as_float((unsigned)(g3 >> 17));
    float v4 = __uint_as_float((unsigned)(g4 >> 17));

    // emit idx1
    if (wg == 0 && tid == 0) cross_inds[b * KFPS + t] = i1;
    ++t; w = i1;
    if (t >= KFPS) break;

    // candidate coords (uniform loads)
    float e0x = pb[3 * i1 + 0], e0y = pb[3 * i1 + 1], e0z = pb[3 * i1 + 2];

    // ---- chain step 2 ----
    {
      float cx = pb[3 * i2 + 0], cy = pb[3 * i2 + 1], cz = pb[3 * i2 + 2];
      float dx = __fsub_rn(cx, e0x), dy = __fsub_rn(cy, e0y), dz = __fsub_rn(cz, e0z);
      float d2 = __fadd_rn(__fadd_rn(__fmul_rn(dx, dx), __fmul_rn(dy, dy)), __fmul_rn(dz, dz));
      if (!((v2 > 0.f) && (d2 >= v2) && (i2 != i1))) continue;
      FOLD(e0x, e0y, e0z);                 // fold e0 = i1
      if (wg == 0 && tid == 0) cross_inds[b * KFPS + t] = i2;
      ++t; w = i2;
      if (t >= KFPS) break;
    }
    float e1x = pb[3 * i2 + 0], e1y = pb[3 * i2 + 1], e1z = pb[3 * i2 + 2];

    // ---- chain step 3 ----
    {
      float cx = pb[3 * i3 + 0], cy = pb[3 * i3 + 1], cz = pb[3 * i3 + 2];
      float ax = __fsub_rn(cx, e0x), ay = __fsub_rn(cy, e0y), az = __fsub_rn(cz, e0z);
      float da = __fadd_rn(__fadd_rn(__fmul_rn(ax, ax), __fmul_rn(ay, ay)), __fmul_rn(az, az));
      float bx = __fsub_rn(cx, e1x), by = __fsub_rn(cy, e1y), bz = __fsub_rn(cz, e1z);
      float db = __fadd_rn(__fadd_rn(__fmul_rn(bx, bx), __fmul_rn(by, by)), __fmul_rn(bz, bz));
      if (!((v3 > 0.f) && (da >= v3) && (db >= v3))) continue;
      FOLD(e1x, e1y, e1z);                 // fold e1 = i2
      if (wg == 0 && tid == 0) cross_inds[b * KFPS + t] = i3;
      ++t; w = i3;
      if (t >= KFPS) break;
    }
    float e2x = pb[3 * i3 + 0], e2y = pb[3 * i3 + 1], e2z = pb[3 * i3 + 2];

    // ---- chain step 4 ----
    {
      float cx = pb[3 * i4 + 0], cy = pb[3 * i4 + 1], cz = pb[3 * i4 + 2];
      float ax = __fsub_rn(cx, e0x), ay = __fsub_rn(cy, e0y), az = __fsub_rn(cz, e0z);
      float da = __fadd_rn(__fadd_rn(__fmul_rn(ax, ax), __fmul_rn(ay, ay)), __fmul_rn(az, az));
      float bx = __fsub_rn(cx, e1x), by = __fsub_rn(cy, e1y), bz = __fsub_rn(cz, e1z);
      float db = __fadd_rn(__fadd_rn(__fmul_rn(bx, bx), __fmul_rn(by, by)), __fmul_rn(bz, bz));
      float gx = __fsub_rn(cx, e2x), gy = __fsub_rn(cy, e2y), gz = __fsub_rn(cz, e2z);
      float dg = __fadd_rn(__fadd_rn(__fmul_rn(gx, gx), __fmul_rn(gy, gy)), __fmul_rn(gz, gz));
      if (!((v4 > 0.f) && (da >= v4) && (db >= v4) && (dg >= v4))) continue;
      FOLD(e2x, e2y, e2z);                 // fold e2 = i3
      if (wg == 0 && tid == 0) cross_inds[b * KFPS + t] = i4;
      ++t; w = i4;
    }
  }
  #undef FOLD
}

// ============================================================
// Kernel 4: gathers (feats_sel, pts_sel, cross_features)
// ============================================================
#define GF4 ((NB * (KTOP + KFPS)) * (ND / 4))   // 589824 float4 gathers
#define GPTS (NB * KTOP * 3)                    // 6144

__global__ void k_gather(const float* __restrict__ pts,
                         const float* __restrict__ feat,
                         const int* __restrict__ sorti,
                         const int* __restrict__ crossi,
                         float* __restrict__ out) {
  int id = blockIdx.x * 256 + threadIdx.x;
  if (id < GF4) {
    int row = id >> 5, c4 = id & 31;
    int b, s; float* dst;
    if (row < NB * KTOP) {
      b = row >> 8;
      s = sorti[row];
      dst = out + OUT_FEATS + (size_t)row * ND;
    } else {
      int r2 = row - NB * KTOP;
      b = r2 >> 11;
      s = crossi[r2];
      dst = out + OUT_CROSS + (size_t)r2 * ND;
    }
    if (s < 0 || s >= NPTS) s = 0;
    float4 v = ((const float4*)(feat + ((size_t)b * NPTS + (size_t)s) * ND))[c4];
    ((float4*)dst)[c4] = v;
  } else if (id < GF4 + GPTS) {
    int q = id - GF4;
    int row = q / 3, d = q - row * 3;
    int b = row >> 8;
    int s = sorti[row];
    if (s < 0 || s >= NPTS) s = 0;
    out[OUT_PTS + q] = pts[((size_t)b * NPTS + (size_t)s) * 3 + d];
  }
}

// ============================================================
extern "C" void kernel_launch(void* const* d_in, const int* in_sizes, int n_in,
                              void* d_out, int out_size, void* d_ws, size_t ws_size,
                              hipStream_t stream) {
  const float* cent = (const float*)d_in[0];
  const float* cls  = (const float*)d_in[1];
  const float* pts  = (const float*)d_in[2];
  const float* feat = (const float*)d_in[3];
  float* out = (float*)d_out;

  unsigned long long* partials = (unsigned long long*)(out + OUT_PART);
  int* cross_ws = (int*)((char*)d_ws + WS_CROSS);
  int* sorti_ws = (int*)((char*)d_ws + WS_SORTI);
  float* scores = out + OUT_SCORES;

  hipLaunchKernelGGL(k_init, dim3((PART_U64 + 255) / 256), dim3(256), 0, stream,
                     partials);
  hipLaunchKernelGGL(k_scores, dim3((NB * NPTS + 255) / 256), dim3(256), 0, stream,
                     cent, cls, scores);
  hipLaunchKernelGGL(k_topk, dim3(NB), dim3(1024), 0, stream,
                     scores, sorti_ws, out + OUT_INDS);
  hipLaunchKernelGGL(k_fps, dim3(NB * FWGS), dim3(FTHR), 0, stream,
                     pts, partials, cross_ws);
  int gtot = GF4 + GPTS;
  hipLaunchKernelGGL(k_gather, dim3((gtot + 255) / 256), dim3(256), 0, stream,
                     pts, feat, sorti_ws, cross_ws, out);
}

// Round 15
// 4022.074 us; speedup vs baseline: 1.0692x; 1.0692x over previous
//
#include <hip/hip_runtime.h>
#include <math.h>

// ---------------- problem constants ----------------
#define NB    8
#define NPTS  100000
#define NCLS  18
#define ND    128
#define KFPS  2048
#define KTOP  256

// ---------------- FPS config ----------------
#define FWGS       32                 // workgroups per batch
#define FTHR       256                // threads per WG
#define FBTHREADS  (FWGS*FTHR)        // 8192 threads per batch
#define PPT        13                 // points per thread (13*8192 >= 100000)
#define NSLOT      32                 // one slot (4 records) per WG per batch
#define RSTRIDE    64                 // u64s per slot (512 B) -> MALL slice spread
#define TAG_SHIFT  49
#define KEY_MASK   ((1ull<<TAG_SHIFT)-1)
#define IDX_MASK   0x1FFFFull
#define INVALID_REC (~0ull)           // tag 0x7FFF: never matches live tags

// per-batch u64 region: 2 banks x 32 slots x 64 u64-stride (slot holds 4 recs)
#define BANK_U64   (NSLOT * RSTRIDE)            // 2048
#define B_TOTAL    (2 * BANK_U64)               // 4096
#define PART_U64   (NB * B_TOTAL)               // 32768 u64 = 256 KB

static_assert(PPT * FBTHREADS >= NPTS, "coverage");

// ---------------- out layout (float elements), total 2367488 ----------------
#define OUT_PTS    0          // 8*256*3    = 6144
#define OUT_FEATS  6144       // 8*256*128  = 262144
#define OUT_INDS   268288     // 8*256      = 2048
#define OUT_CROSS  270336     // 8*2048*128 = 2097152
// scratch INSIDE region 3 (overwritten by k_gather at the end):
#define OUT_SCORES OUT_CROSS              // 800000 floats
#define OUT_PART   (OUT_CROSS + 800000)   // 8B-aligned
static_assert((OUT_PART % 2) == 0, "u64 alignment");
static_assert(OUT_PART + PART_U64 * 2 <= OUT_CROSS + 2097152, "fits in region 3");

// ---------------- ws layout (bytes) — proven-safe 90112 ----------------
#define WS_CROSS    16384                   // NB*KFPS*4 = 65536
#define WS_SORTI    (16384+65536)           // NB*KTOP*4 = 8192   (end 90112)

typedef unsigned int uint32x4 __attribute__((ext_vector_type(4)));

// one 16B MALL-coherent load -> two u64 records, single round trip.
// sc0 sc1 = system scope (superset of agent). Tag-in-u64 self-verifies
// freshness; wrong/stale data can only cause a retry, never corruption.
__device__ __forceinline__ void ld16_mall(const unsigned long long* p,
                                          unsigned long long& lo,
                                          unsigned long long& hi) {
  uint32x4 v;
  asm volatile("global_load_dwordx4 %0, %1, off sc0 sc1\n\ts_waitcnt vmcnt(0)"
               : "=v"(v) : "v"((unsigned long long)p) : "memory");
  lo = ((unsigned long long)v.y << 32) | (unsigned long long)v.x;
  hi = ((unsigned long long)v.w << 32) | (unsigned long long)v.z;
}

// ============================================================
// Kernel 0: init record slots (runs before k_fps every call)
// ============================================================
__global__ void k_init(unsigned long long* __restrict__ partials) {
  int id = blockIdx.x * 256 + threadIdx.x;
  if (id < PART_U64)
    __hip_atomic_store(&partials[id], INVALID_REC,
                       __ATOMIC_RELAXED, __HIP_MEMORY_SCOPE_AGENT);
}

// ============================================================
// Kernel 1: max_scores = sigmoid(max_c cls) * sigmoid(centerness)
// ============================================================
__global__ void k_scores(const float* __restrict__ cent,
                         const float* __restrict__ cls,
                         float* __restrict__ scores) {
  int gid = blockIdx.x * blockDim.x + threadIdx.x;
  if (gid >= NB * NPTS) return;
  const float* c = cls + (size_t)gid * NCLS;
  float m = c[0];
  #pragma unroll
  for (int i = 1; i < NCLS; ++i) m = fmaxf(m, c[i]);
  double sm = 1.0 / (1.0 + exp(-(double)m));
  double sc = 1.0 / (1.0 + exp(-(double)cent[gid]));
  scores[gid] = __fmul_rn((float)sm, (float)sc);
}

// ============================================================
// Kernel 2: per-batch exact top-256 (value desc, idx asc), output sorted idx
// ============================================================
__global__ __launch_bounds__(1024) void k_topk(const float* __restrict__ scores,
                                               int* __restrict__ sorti_ws,
                                               float* __restrict__ out_inds) {
  __shared__ unsigned hist[2048];
  __shared__ int candG[256];
  __shared__ int candE[512];
  __shared__ unsigned s_cg, s_ce, s_bin, s_rank;

  int b = blockIdx.x;
  int tid = threadIdx.x;
  const float* sb = scores + (size_t)b * NPTS;

  unsigned prefix = 0, pmask = 0;
  int r = KTOP;
  for (int pass = 0; pass < 3; ++pass) {
    int shift = (pass == 0) ? 21 : (pass == 1) ? 10 : 0;
    int bins  = (pass < 2) ? 2048 : 1024;
    for (int i = tid; i < bins; i += 1024) hist[i] = 0;
    __syncthreads();
    for (int n = tid; n < NPTS; n += 1024) {
      unsigned k = __float_as_uint(sb[n]);
      if ((k & pmask) == prefix) atomicAdd(&hist[(k >> shift) & (bins - 1)], 1u);
    }
    __syncthreads();
    if (tid == 0) {
      unsigned c = 0; int bin = bins - 1;
      for (; bin > 0; --bin) { unsigned h = hist[bin]; if (c + h >= (unsigned)r) break; c += h; }
      s_bin = (unsigned)bin; s_rank = (unsigned)r - c;
    }
    __syncthreads();
    prefix |= s_bin << shift;
    pmask  |= (unsigned)(bins - 1) << shift;
    r = (int)s_rank;
    __syncthreads();
  }
  unsigned T = prefix;
  int need = r;
  int nG = KTOP - need;

  if (tid == 0) { s_cg = 0; s_ce = 0; }
  __syncthreads();
  for (int n = tid; n < NPTS; n += 1024) {
    unsigned k = __float_as_uint(sb[n]);
    if (k > T)       { unsigned p = atomicAdd(&s_cg, 1u); if (p < 256) candG[p] = n; }
    else if (k == T) { unsigned p = atomicAdd(&s_ce, 1u); if (p < 512) candE[p] = n; }
  }
  __syncthreads();
  unsigned ce = s_ce;
  for (int i = tid; i < 512; i += 1024) if (i >= (int)ce) candE[i] = 0x7FFFFFFF;
  __syncthreads();
  for (int k2 = 2; k2 <= 512; k2 <<= 1)
    for (int j = k2 >> 1; j >= 1; j >>= 1) {
      if (tid < 512) {
        int i = tid, p = i ^ j;
        if (p > i) {
          int a = candE[i], bb = candE[p];
          bool up = ((i & k2) == 0);
          if ((a > bb) == up) { candE[i] = bb; candE[p] = a; }
        }
      }
      __syncthreads();
    }
  int* arr = (int*)hist;
  if (tid < KTOP) arr[tid] = (tid < nG) ? candG[tid] : candE[tid - nG];
  __syncthreads();
  for (int k2 = 2; k2 <= 256; k2 <<= 1)
    for (int j = k2 >> 1; j >= 1; j >>= 1) {
      if (tid < 256) {
        int i = tid, p = i ^ j;
        if (p > i) {
          int a = arr[i], bb = arr[p];
          bool up = ((i & k2) == 0);
          if ((a > bb) == up) { arr[i] = bb; arr[p] = a; }
        }
      }
      __syncthreads();
    }
  if (tid < KTOP) {
    sorti_ws[b * KTOP + tid] = arr[tid];
    out_inds[b * KTOP + tid] = (float)arr[tid];
  }
}

// ---- compare-exchange (keep x >= y) and top-4 merge of two desc lists ----
__device__ __forceinline__ void ce_u64(unsigned long long& x, unsigned long long& y) {
  unsigned long long mx = (x > y) ? x : y;
  unsigned long long mn = (x > y) ? y : x;
  x = mx; y = mn;
}
__device__ __forceinline__ void merge4(unsigned long long& a1, unsigned long long& a2,
                                       unsigned long long& a3, unsigned long long& a4,
                                       unsigned long long b1, unsigned long long b2,
                                       unsigned long long b3, unsigned long long b4) {
  unsigned long long t1 = (a1 > b4) ? a1 : b4;
  unsigned long long t2 = (a2 > b3) ? a2 : b3;
  unsigned long long t3 = (a3 > b2) ? a3 : b2;
  unsigned long long t4 = (a4 > b1) ? a4 : b1;
  ce_u64(t1, t3); ce_u64(t2, t4); ce_u64(t1, t2); ce_u64(t3, t4);
  a1 = t1; a2 = t2; a3 = t3; a4 = t4;
}

// ============================================================
// Kernel 3: FPS, exact top-4 lookahead chain (r14) + 1-transaction poll:
// 64 lanes x one 16B dwordx4 load cover all 128 records per sweep
// (r11-parity MALL queue pressure). Fallback to proven per-record
// atomic loads after 6 failed fast sweeps (flag-safety; any mix OK).
// Tag = consensus counter + 1; ping-pong banks; bounded spins; clamps.
// ============================================================
__global__ __launch_bounds__(FTHR, 1) void k_fps(const float* __restrict__ points,
                                                 unsigned long long* __restrict__ partials,
                                                 int* __restrict__ cross_inds) {
  int b    = blockIdx.x & 7;
  int wg   = blockIdx.x >> 3;    // 0..31
  int tid  = threadIdx.x;
  int lane = tid & 63;
  int wave = tid >> 6;           // 0..3
  int gthr = wg * FTHR + tid;

  __shared__ unsigned long long lred[4][4];
  __shared__ unsigned long long lg[4];

  const float* pb = points + (size_t)b * NPTS * 3;
  unsigned long long* base = partials + (size_t)b * B_TOTAL;

  float px[PPT], py[PPT], pz[PPT], dd[PPT];
  #pragma unroll
  for (int i = 0; i < PPT; ++i) {
    int n = gthr + i * FBTHREADS;
    bool v = (n < NPTS);
    px[i] = v ? pb[3 * n + 0] : 0.f;
    py[i] = v ? pb[3 * n + 1] : 0.f;
    pz[i] = v ? pb[3 * n + 2] : 0.f;
    dd[i] = 1e10f;
  }
  if (wg == 0 && tid == 0) cross_inds[b * KFPS] = 0;

  #define FOLD(fx, fy, fz) do {                                               \
    _Pragma("unroll")                                                         \
    for (int i_ = 0; i_ < PPT; ++i_) {                                        \
      float dx_ = __fsub_rn(px[i_], (fx));                                    \
      float dy_ = __fsub_rn(py[i_], (fy));                                    \
      float dz_ = __fsub_rn(pz[i_], (fz));                                    \
      float s_  = __fadd_rn(__fadd_rn(__fmul_rn(dx_, dx_), __fmul_rn(dy_, dy_)), \
                            __fmul_rn(dz_, dz_));                             \
      dd[i_] = fminf(dd[i_], s_);                                             \
    }                                                                         \
  } while (0)

  int w = 0;          // emitted, to fold at next update pass
  int t = 1;          // next emission slot
  int c = 0;          // consensus counter
  while (t < KFPS) {
    float wx = pb[3 * w + 0];
    float wy = pb[3 * w + 1];
    float wz = pb[3 * w + 2];

    // update pass + per-thread top-4 (packed (val,~idx) keys, desc s1..s4)
    unsigned long long s1 = 0ull, s2 = 0ull, s3 = 0ull, s4 = 0ull;
    #pragma unroll
    for (int i = 0; i < PPT; ++i) {
      int n = gthr + i * FBTHREADS;
      float dx = __fsub_rn(px[i], wx);
      float dy = __fsub_rn(py[i], wy);
      float dz = __fsub_rn(pz[i], wz);
      float s  = __fadd_rn(__fadd_rn(__fmul_rn(dx, dx), __fmul_rn(dy, dy)), __fmul_rn(dz, dz));
      float nd = fminf(dd[i], s);
      dd[i] = nd;
      if (n < NPTS) {
        unsigned long long k = ((unsigned long long)__float_as_uint(nd) << 17) |
                               (unsigned long long)(0x1FFFFu ^ (unsigned)n);
        s4 = (k > s4) ? k : s4;
        ce_u64(s3, s4); ce_u64(s2, s3); ce_u64(s1, s2);
      }
    }
    // wave butterfly top-4
    #pragma unroll
    for (int off = 32; off >= 1; off >>= 1) {
      unsigned long long o1 = __shfl_xor(s1, off);
      unsigned long long o2 = __shfl_xor(s2, off);
      unsigned long long o3 = __shfl_xor(s3, off);
      unsigned long long o4 = __shfl_xor(s4, off);
      merge4(s1, s2, s3, s4, o1, o2, o3, o4);
    }
    if (lane == 0) { lred[wave][0] = s1; lred[wave][1] = s2;
                     lred[wave][2] = s3; lred[wave][3] = s4; }
    __syncthreads();                       // B1

    unsigned tag = (unsigned)c + 1u;
    unsigned long long* bank = base + (size_t)(c & 1) * BANK_U64;
    if (wave == 0) {
      unsigned long long rc[4] = {0, 0, 0, 0};
      if (lane == 0) {
        unsigned long long m1 = lred[0][0], m2 = lred[0][1],
                           m3 = lred[0][2], m4 = lred[0][3];
        merge4(m1, m2, m3, m4, lred[1][0], lred[1][1], lred[1][2], lred[1][3]);
        merge4(m1, m2, m3, m4, lred[2][0], lred[2][1], lred[2][2], lred[2][3]);
        merge4(m1, m2, m3, m4, lred[3][0], lred[3][1], lred[3][2], lred[3][3]);
        rc[0] = ((unsigned long long)tag << TAG_SHIFT) | m1;
        rc[1] = ((unsigned long long)tag << TAG_SHIFT) | m2;
        rc[2] = ((unsigned long long)tag << TAG_SHIFT) | m3;
        rc[3] = ((unsigned long long)tag << TAG_SHIFT) | m4;
        #pragma unroll
        for (int q = 0; q < 4; ++q)
          __hip_atomic_store(&bank[(size_t)wg * RSTRIDE + q], rc[q],
                             __ATOMIC_RELAXED, __HIP_MEMORY_SCOPE_AGENT);
      }
      // 1-transaction sweep: lane l reads records 2l,2l+1 (slot l>>1)
      unsigned long long ra = 0, rb = 0;
      unsigned long long* ap = &bank[(size_t)(lane >> 1) * RSTRIDE + (size_t)(lane & 1) * 2];
      int spins = 0, sweep = 0;
      for (;;) {
        if (sweep < 6) {
          ld16_mall(ap, ra, rb);                 // fast path: single 16B load
        } else {
          ra = __hip_atomic_load(ap + 0, __ATOMIC_RELAXED, __HIP_MEMORY_SCOPE_AGENT);
          rb = __hip_atomic_load(ap + 1, __ATOMIC_RELAXED, __HIP_MEMORY_SCOPE_AGENT);
        }
        ++sweep;
        bool ok = (((unsigned)(ra >> TAG_SHIFT) == tag) &&
                   ((unsigned)(rb >> TAG_SHIFT) == tag));
        if (__all((int)ok)) break;
        ++spins;
        if (spins > (1 << 11)) break;            // bounded: clamped result, never hangs
        if ((spins & 255) == 0 && lane == 0) {   // heal lost stores (proven path)
          #pragma unroll
          for (int q = 0; q < 4; ++q)
            __hip_atomic_store(&bank[(size_t)wg * RSTRIDE + q], rc[q],
                               __ATOMIC_RELAXED, __HIP_MEMORY_SCOPE_AGENT);
        }
        if (spins > 512) __builtin_amdgcn_s_sleep(1);
      }
      // global top-4: each lane contributes its desc pair padded to a 4-list
      unsigned long long k1 = ra & KEY_MASK;
      unsigned long long k2 = rb & KEY_MASK;
      unsigned long long k3 = 0ull, k4 = 0ull;
      #pragma unroll
      for (int off = 32; off >= 1; off >>= 1) {
        unsigned long long o1 = __shfl_xor(k1, off);
        unsigned long long o2 = __shfl_xor(k2, off);
        unsigned long long o3 = __shfl_xor(k3, off);
        unsigned long long o4 = __shfl_xor(k4, off);
        merge4(k1, k2, k3, k4, o1, o2, o3, o4);
      }
      if (lane == 0) { lg[0] = k1; lg[1] = k2; lg[2] = k3; lg[3] = k4; }
    }
    __syncthreads();                       // B2
    unsigned long long g1 = lg[0], g2 = lg[1], g3 = lg[2], g4 = lg[3];
    ++c;

    int i1 = (int)(0x1FFFFu ^ (unsigned)(g1 & IDX_MASK));
    int i2 = (int)(0x1FFFFu ^ (unsigned)(g2 & IDX_MASK));
    int i3 = (int)(0x1FFFFu ^ (unsigned)(g3 & IDX_MASK));
    int i4 = (int)(0x1FFFFu ^ (unsigned)(g4 & IDX_MASK));
    if (i1 >= NPTS) i1 = 0;                // safety: never OOB
    if (i2 >= NPTS) i2 = 0;
    if (i3 >= NPTS) i3 = 0;
    if (i4 >= NPTS) i4 = 0;
    float v2 = __uint_as_float((unsigned)(g2 >> 17));
    float v3 = __uint_as_float((unsigned)(g3 >> 17));
    float v4 = __uint_as_float((unsigned)(g4 >> 17));

    // emit idx1
    if (wg == 0 && tid == 0) cross_inds[b * KFPS + t] = i1;
    ++t; w = i1;
    if (t >= KFPS) break;

    float e0x = pb[3 * i1 + 0], e0y = pb[3 * i1 + 1], e0z = pb[3 * i1 + 2];

    // ---- chain step 2 ----
    {
      float cx = pb[3 * i2 + 0], cy = pb[3 * i2 + 1], cz = pb[3 * i2 + 2];
      float dx = __fsub_rn(cx, e0x), dy = __fsub_rn(cy, e0y), dz = __fsub_rn(cz, e0z);
      float d2 = __fadd_rn(__fadd_rn(__fmul_rn(dx, dx), __fmul_rn(dy, dy)), __fmul_rn(dz, dz));
      if (!((v2 > 0.f) && (d2 >= v2) && (i2 != i1))) continue;
      FOLD(e0x, e0y, e0z);                 // fold e0 = i1
      if (wg == 0 && tid == 0) cross_inds[b * KFPS + t] = i2;
      ++t; w = i2;
      if (t >= KFPS) break;
    }
    float e1x = pb[3 * i2 + 0], e1y = pb[3 * i2 + 1], e1z = pb[3 * i2 + 2];

    // ---- chain step 3 ----
    {
      float cx = pb[3 * i3 + 0], cy = pb[3 * i3 + 1], cz = pb[3 * i3 + 2];
      float ax = __fsub_rn(cx, e0x), ay = __fsub_rn(cy, e0y), az = __fsub_rn(cz, e0z);
      float da = __fadd_rn(__fadd_rn(__fmul_rn(ax, ax), __fmul_rn(ay, ay)), __fmul_rn(az, az));
      float bx = __fsub_rn(cx, e1x), by = __fsub_rn(cy, e1y), bz = __fsub_rn(cz, e1z);
      float db = __fadd_rn(__fadd_rn(__fmul_rn(bx, bx), __fmul_rn(by, by)), __fmul_rn(bz, bz));
      if (!((v3 > 0.f) && (da >= v3) && (db >= v3))) continue;
      FOLD(e1x, e1y, e1z);                 // fold e1 = i2
      if (wg == 0 && tid == 0) cross_inds[b * KFPS + t] = i3;
      ++t; w = i3;
      if (t >= KFPS) break;
    }
    float e2x = pb[3 * i3 + 0], e2y = pb[3 * i3 + 1], e2z = pb[3 * i3 + 2];

    // ---- chain step 4 ----
    {
      float cx = pb[3 * i4 + 0], cy = pb[3 * i4 + 1], cz = pb[3 * i4 + 2];
      float ax = __fsub_rn(cx, e0x), ay = __fsub_rn(cy, e0y), az = __fsub_rn(cz, e0z);
      float da = __fadd_rn(__fadd_rn(__fmul_rn(ax, ax), __fmul_rn(ay, ay)), __fmul_rn(az, az));
      float bx = __fsub_rn(cx, e1x), by = __fsub_rn(cy, e1y), bz = __fsub_rn(cz, e1z);
      float db = __fadd_rn(__fadd_rn(__fmul_rn(bx, bx), __fmul_rn(by, by)), __fmul_rn(bz, bz));
      float gx = __fsub_rn(cx, e2x), gy = __fsub_rn(cy, e2y), gz = __fsub_rn(cz, e2z);
      float dg = __fadd_rn(__fadd_rn(__fmul_rn(gx, gx), __fmul_rn(gy, gy)), __fmul_rn(gz, gz));
      if (!((v4 > 0.f) && (da >= v4) && (db >= v4) && (dg >= v4))) continue;
      FOLD(e2x, e2y, e2z);                 // fold e2 = i3
      if (wg == 0 && tid == 0) cross_inds[b * KFPS + t] = i4;
      ++t; w = i4;
    }
  }
  #undef FOLD
}

// ============================================================
// Kernel 4: gathers (feats_sel, pts_sel, cross_features)
// ============================================================
#define GF4 ((NB * (KTOP + KFPS)) * (ND / 4))   // 589824 float4 gathers
#define GPTS (NB * KTOP * 3)                    // 6144

__global__ void k_gather(const float* __restrict__ pts,
                         const float* __restrict__ feat,
                         const int* __restrict__ sorti,
                         const int* __restrict__ crossi,
                         float* __restrict__ out) {
  int id = blockIdx.x * 256 + threadIdx.x;
  if (id < GF4) {
    int row = id >> 5, c4 = id & 31;
    int b, s; float* dst;
    if (row < NB * KTOP) {
      b = row >> 8;
      s = sorti[row];
      dst = out + OUT_FEATS + (size_t)row * ND;
    } else {
      int r2 = row - NB * KTOP;
      b = r2 >> 11;
      s = crossi[r2];
      dst = out + OUT_CROSS + (size_t)r2 * ND;
    }
    if (s < 0 || s >= NPTS) s = 0;
    float4 v = ((const float4*)(feat + ((size_t)b * NPTS + (size_t)s) * ND))[c4];
    ((float4*)dst)[c4] = v;
  } else if (id < GF4 + GPTS) {
    int q = id - GF4;
    int row = q / 3, d = q - row * 3;
    int b = row >> 8;
    int s = sorti[row];
    if (s < 0 || s >= NPTS) s = 0;
    out[OUT_PTS + q] = pts[((size_t)b * NPTS + (size_t)s) * 3 + d];
  }
}

// ============================================================
extern "C" void kernel_launch(void* const* d_in, const int* in_sizes, int n_in,
                              void* d_out, int out_size, void* d_ws, size_t ws_size,
                              hipStream_t stream) {
  const float* cent = (const float*)d_in[0];
  const float* cls  = (const float*)d_in[1];
  const float* pts  = (const float*)d_in[2];
  const float* feat = (const float*)d_in[3];
  float* out = (float*)d_out;

  unsigned long long* partials = (unsigned long long*)(out + OUT_PART);
  int* cross_ws = (int*)((char*)d_ws + WS_CROSS);
  int* sorti_ws = (int*)((char*)d_ws + WS_SORTI);
  float* scores = out + OUT_SCORES;

  hipLaunchKernelGGL(k_init, dim3((PART_U64 + 255) / 256), dim3(256), 0, stream,
                     partials);
  hipLaunchKernelGGL(k_scores, dim3((NB * NPTS + 255) / 256), dim3(256), 0, stream,
                     cent, cls, scores);
  hipLaunchKernelGGL(k_topk, dim3(NB), dim3(1024), 0, stream,
                     scores, sorti_ws, out + OUT_INDS);
  hipLaunchKernelGGL(k_fps, dim3(NB * FWGS), dim3(FTHR), 0, stream,
                     pts, partials, cross_ws);
  int gtot = GF4 + GPTS;
  hipLaunchKernelGGL(k_gather, dim3((gtot + 255) / 256), dim3(256), 0, stream,
                     pts, feat, sorti_ws, cross_ws, out);
}

// Round 16
// 3843.193 us; speedup vs baseline: 1.1190x; 1.0465x over previous
//
#include <hip/hip_runtime.h>
#include <math.h>

// ---------------- problem constants ----------------
#define NB    8
#define NPTS  100000
#define NCLS  18
#define ND    128
#define KFPS  2048
#define KTOP  256

// ---------------- FPS config ----------------
#define FWGS       32                 // workgroups per batch
#define FTHR       256                // threads per WG
#define FBTHREADS  (FWGS*FTHR)        // 8192 threads per batch
#define PPT        13                 // points per thread (13*8192 >= 100000)
#define NSLOT      32                 // one slot (4 records) per WG per batch
#define RSTRIDE    64                 // u64s per slot (512 B) -> MALL slice spread
#define TAG_SHIFT  49
#define KEY_MASK   ((1ull<<TAG_SHIFT)-1)
#define IDX_MASK   0x1FFFFull
#define INVALID_REC (~0ull)           // tag 0x7FFF: never matches live tags

// per-batch u64 region: 2 banks x 32 slots x 64 u64-stride (slot holds 4 recs)
#define BANK_U64   (NSLOT * RSTRIDE)            // 2048
#define B_TOTAL    (2 * BANK_U64)               // 4096
#define PART_U64   (NB * B_TOTAL)               // 32768 u64 = 256 KB

static_assert(PPT * FBTHREADS >= NPTS, "coverage");

// ---------------- out layout (float elements), total 2367488 ----------------
#define OUT_PTS    0          // 8*256*3    = 6144
#define OUT_FEATS  6144       // 8*256*128  = 262144
#define OUT_INDS   268288     // 8*256      = 2048
#define OUT_CROSS  270336     // 8*2048*128 = 2097152
// scratch INSIDE region 3 (overwritten by k_gather at the end):
#define OUT_SCORES OUT_CROSS              // 800000 floats
#define OUT_PART   (OUT_CROSS + 800000)   // 8B-aligned
static_assert((OUT_PART % 2) == 0, "u64 alignment");
static_assert(OUT_PART + PART_U64 * 2 <= OUT_CROSS + 2097152, "fits in region 3");

// ---------------- ws layout (bytes) — proven-safe 90112 ----------------
#define WS_CROSS    16384                   // NB*KFPS*4 = 65536
#define WS_SORTI    (16384+65536)           // NB*KTOP*4 = 8192   (end 90112)

typedef unsigned int uint32x4 __attribute__((ext_vector_type(4)));

// one 16B MALL-coherent load -> two u64 records, single round trip.
// Validated bit-exact in r15. Tag-in-u64 self-verifies freshness.
__device__ __forceinline__ void ld16_mall(const unsigned long long* p,
                                          unsigned long long& lo,
                                          unsigned long long& hi) {
  uint32x4 v;
  asm volatile("global_load_dwordx4 %0, %1, off sc0 sc1\n\ts_waitcnt vmcnt(0)"
               : "=v"(v) : "v"((unsigned long long)p) : "memory");
  lo = ((unsigned long long)v.y << 32) | (unsigned long long)v.x;
  hi = ((unsigned long long)v.w << 32) | (unsigned long long)v.z;
}
// one 16B store publishing two tagged records in a single transaction.
// No atomicity needed: each u64 half has its own tag (partial -> retry).
// If visibility fails, pollers heal via proven atomic stores (bounded).
__device__ __forceinline__ void st16_mall(unsigned long long* p,
                                          unsigned long long lo,
                                          unsigned long long hi) {
  uint32x4 v;
  v.x = (unsigned)lo; v.y = (unsigned)(lo >> 32);
  v.z = (unsigned)hi; v.w = (unsigned)(hi >> 32);
  asm volatile("global_store_dwordx4 %0, %1, off sc0 sc1"
               :: "v"((unsigned long long)p), "v"(v) : "memory");
}

// ============================================================
// Kernel 0: init record slots (runs before k_fps every call)
// ============================================================
__global__ void k_init(unsigned long long* __restrict__ partials) {
  int id = blockIdx.x * 256 + threadIdx.x;
  if (id < PART_U64)
    __hip_atomic_store(&partials[id], INVALID_REC,
                       __ATOMIC_RELAXED, __HIP_MEMORY_SCOPE_AGENT);
}

// ============================================================
// Kernel 1: max_scores = sigmoid(max_c cls) * sigmoid(centerness)
// ============================================================
__global__ void k_scores(const float* __restrict__ cent,
                         const float* __restrict__ cls,
                         float* __restrict__ scores) {
  int gid = blockIdx.x * blockDim.x + threadIdx.x;
  if (gid >= NB * NPTS) return;
  const float* c = cls + (size_t)gid * NCLS;
  float m = c[0];
  #pragma unroll
  for (int i = 1; i < NCLS; ++i) m = fmaxf(m, c[i]);
  double sm = 1.0 / (1.0 + exp(-(double)m));
  double sc = 1.0 / (1.0 + exp(-(double)cent[gid]));
  scores[gid] = __fmul_rn((float)sm, (float)sc);
}

// ============================================================
// Kernel 2: per-batch exact top-256 (value desc, idx asc), output sorted idx
// ============================================================
__global__ __launch_bounds__(1024) void k_topk(const float* __restrict__ scores,
                                               int* __restrict__ sorti_ws,
                                               float* __restrict__ out_inds) {
  __shared__ unsigned hist[2048];
  __shared__ int candG[256];
  __shared__ int candE[512];
  __shared__ unsigned s_cg, s_ce, s_bin, s_rank;

  int b = blockIdx.x;
  int tid = threadIdx.x;
  const float* sb = scores + (size_t)b * NPTS;

  unsigned prefix = 0, pmask = 0;
  int r = KTOP;
  for (int pass = 0; pass < 3; ++pass) {
    int shift = (pass == 0) ? 21 : (pass == 1) ? 10 : 0;
    int bins  = (pass < 2) ? 2048 : 1024;
    for (int i = tid; i < bins; i += 1024) hist[i] = 0;
    __syncthreads();
    for (int n = tid; n < NPTS; n += 1024) {
      unsigned k = __float_as_uint(sb[n]);
      if ((k & pmask) == prefix) atomicAdd(&hist[(k >> shift) & (bins - 1)], 1u);
    }
    __syncthreads();
    if (tid == 0) {
      unsigned c = 0; int bin = bins - 1;
      for (; bin > 0; --bin) { unsigned h = hist[bin]; if (c + h >= (unsigned)r) break; c += h; }
      s_bin = (unsigned)bin; s_rank = (unsigned)r - c;
    }
    __syncthreads();
    prefix |= s_bin << shift;
    pmask  |= (unsigned)(bins - 1) << shift;
    r = (int)s_rank;
    __syncthreads();
  }
  unsigned T = prefix;
  int need = r;
  int nG = KTOP - need;

  if (tid == 0) { s_cg = 0; s_ce = 0; }
  __syncthreads();
  for (int n = tid; n < NPTS; n += 1024) {
    unsigned k = __float_as_uint(sb[n]);
    if (k > T)       { unsigned p = atomicAdd(&s_cg, 1u); if (p < 256) candG[p] = n; }
    else if (k == T) { unsigned p = atomicAdd(&s_ce, 1u); if (p < 512) candE[p] = n; }
  }
  __syncthreads();
  unsigned ce = s_ce;
  for (int i = tid; i < 512; i += 1024) if (i >= (int)ce) candE[i] = 0x7FFFFFFF;
  __syncthreads();
  for (int k2 = 2; k2 <= 512; k2 <<= 1)
    for (int j = k2 >> 1; j >= 1; j >>= 1) {
      if (tid < 512) {
        int i = tid, p = i ^ j;
        if (p > i) {
          int a = candE[i], bb = candE[p];
          bool up = ((i & k2) == 0);
          if ((a > bb) == up) { candE[i] = bb; candE[p] = a; }
        }
      }
      __syncthreads();
    }
  int* arr = (int*)hist;
  if (tid < KTOP) arr[tid] = (tid < nG) ? candG[tid] : candE[tid - nG];
  __syncthreads();
  for (int k2 = 2; k2 <= 256; k2 <<= 1)
    for (int j = k2 >> 1; j >= 1; j >>= 1) {
      if (tid < 256) {
        int i = tid, p = i ^ j;
        if (p > i) {
          int a = arr[i], bb = arr[p];
          bool up = ((i & k2) == 0);
          if ((a > bb) == up) { arr[i] = bb; arr[p] = a; }
        }
      }
      __syncthreads();
    }
  if (tid < KTOP) {
    sorti_ws[b * KTOP + tid] = arr[tid];
    out_inds[b * KTOP + tid] = (float)arr[tid];
  }
}

// ---- compare-exchange (keep x >= y) and top-4 merge of two desc lists ----
__device__ __forceinline__ void ce_u64(unsigned long long& x, unsigned long long& y) {
  unsigned long long mx = (x > y) ? x : y;
  unsigned long long mn = (x > y) ? y : x;
  x = mx; y = mn;
}
__device__ __forceinline__ void merge4(unsigned long long& a1, unsigned long long& a2,
                                       unsigned long long& a3, unsigned long long& a4,
                                       unsigned long long b1, unsigned long long b2,
                                       unsigned long long b3, unsigned long long b4) {
  unsigned long long t1 = (a1 > b4) ? a1 : b4;
  unsigned long long t2 = (a2 > b3) ? a2 : b3;
  unsigned long long t3 = (a3 > b2) ? a3 : b2;
  unsigned long long t4 = (a4 > b1) ? a4 : b1;
  ce_u64(t1, t3); ce_u64(t2, t4); ce_u64(t1, t2); ce_u64(t3, t4);
  a1 = t1; a2 = t2; a3 = t3; a4 = t4;
}

// ============================================================
// Kernel 3: FPS, exact top-4 lookahead chain + minimal-transaction
// consensus: publish = 2 x 16B dwordx4 (was 4 atomic stores, the
// measured 0.37us/store critical-path term); poll = 1 x 16B/lane.
// Fallback/heal via proven per-record atomic ops (any mix correct).
// Tag = consensus counter + 1; ping-pong banks; bounded spins; clamps.
// ============================================================
__global__ __launch_bounds__(FTHR, 1) void k_fps(const float* __restrict__ points,
                                                 unsigned long long* __restrict__ partials,
                                                 int* __restrict__ cross_inds) {
  int b    = blockIdx.x & 7;
  int wg   = blockIdx.x >> 3;    // 0..31
  int tid  = threadIdx.x;
  int lane = tid & 63;
  int wave = tid >> 6;           // 0..3
  int gthr = wg * FTHR + tid;

  __shared__ unsigned long long lred[4][4];
  __shared__ unsigned long long lg[4];

  const float* pb = points + (size_t)b * NPTS * 3;
  unsigned long long* base = partials + (size_t)b * B_TOTAL;

  float px[PPT], py[PPT], pz[PPT], dd[PPT];
  #pragma unroll
  for (int i = 0; i < PPT; ++i) {
    int n = gthr + i * FBTHREADS;
    bool v = (n < NPTS);
    px[i] = v ? pb[3 * n + 0] : 0.f;
    py[i] = v ? pb[3 * n + 1] : 0.f;
    pz[i] = v ? pb[3 * n + 2] : 0.f;
    dd[i] = 1e10f;
  }
  if (wg == 0 && tid == 0) cross_inds[b * KFPS] = 0;

  #define FOLD(fx, fy, fz) do {                                               \
    _Pragma("unroll")                                                         \
    for (int i_ = 0; i_ < PPT; ++i_) {                                        \
      float dx_ = __fsub_rn(px[i_], (fx));                                    \
      float dy_ = __fsub_rn(py[i_], (fy));                                    \
      float dz_ = __fsub_rn(pz[i_], (fz));                                    \
      float s_  = __fadd_rn(__fadd_rn(__fmul_rn(dx_, dx_), __fmul_rn(dy_, dy_)), \
                            __fmul_rn(dz_, dz_));                             \
      dd[i_] = fminf(dd[i_], s_);                                             \
    }                                                                         \
  } while (0)

  int w = 0;          // emitted, to fold at next update pass
  int t = 1;          // next emission slot
  int c = 0;          // consensus counter
  while (t < KFPS) {
    float wx = pb[3 * w + 0];
    float wy = pb[3 * w + 1];
    float wz = pb[3 * w + 2];

    // update pass + per-thread top-4 (packed (val,~idx) keys, desc s1..s4)
    unsigned long long s1 = 0ull, s2 = 0ull, s3 = 0ull, s4 = 0ull;
    #pragma unroll
    for (int i = 0; i < PPT; ++i) {
      int n = gthr + i * FBTHREADS;
      float dx = __fsub_rn(px[i], wx);
      float dy = __fsub_rn(py[i], wy);
      float dz = __fsub_rn(pz[i], wz);
      float s  = __fadd_rn(__fadd_rn(__fmul_rn(dx, dx), __fmul_rn(dy, dy)), __fmul_rn(dz, dz));
      float nd = fminf(dd[i], s);
      dd[i] = nd;
      if (n < NPTS) {
        unsigned long long k = ((unsigned long long)__float_as_uint(nd) << 17) |
                               (unsigned long long)(0x1FFFFu ^ (unsigned)n);
        s4 = (k > s4) ? k : s4;
        ce_u64(s3, s4); ce_u64(s2, s3); ce_u64(s1, s2);
      }
    }
    // wave butterfly top-4
    #pragma unroll
    for (int off = 32; off >= 1; off >>= 1) {
      unsigned long long o1 = __shfl_xor(s1, off);
      unsigned long long o2 = __shfl_xor(s2, off);
      unsigned long long o3 = __shfl_xor(s3, off);
      unsigned long long o4 = __shfl_xor(s4, off);
      merge4(s1, s2, s3, s4, o1, o2, o3, o4);
    }
    if (lane == 0) { lred[wave][0] = s1; lred[wave][1] = s2;
                     lred[wave][2] = s3; lred[wave][3] = s4; }
    __syncthreads();                       // B1

    unsigned tag = (unsigned)c + 1u;
    unsigned long long* bank = base + (size_t)(c & 1) * BANK_U64;
    if (wave == 0) {
      unsigned long long rc[4] = {0, 0, 0, 0};
      if (lane == 0) {
        unsigned long long m1 = lred[0][0], m2 = lred[0][1],
                           m3 = lred[0][2], m4 = lred[0][3];
        merge4(m1, m2, m3, m4, lred[1][0], lred[1][1], lred[1][2], lred[1][3]);
        merge4(m1, m2, m3, m4, lred[2][0], lred[2][1], lred[2][2], lred[2][3]);
        merge4(m1, m2, m3, m4, lred[3][0], lred[3][1], lred[3][2], lred[3][3]);
        rc[0] = ((unsigned long long)tag << TAG_SHIFT) | m1;
        rc[1] = ((unsigned long long)tag << TAG_SHIFT) | m2;
        rc[2] = ((unsigned long long)tag << TAG_SHIFT) | m3;
        rc[3] = ((unsigned long long)tag << TAG_SHIFT) | m4;
        // publish: TWO 16B transactions (critical-path minimal)
        st16_mall(&bank[(size_t)wg * RSTRIDE + 0], rc[0], rc[1]);
        st16_mall(&bank[(size_t)wg * RSTRIDE + 2], rc[2], rc[3]);
      }
      // 1-transaction sweep: lane l reads records 2l,2l+1 (slot l>>1)
      unsigned long long ra = 0, rb = 0;
      unsigned long long* ap = &bank[(size_t)(lane >> 1) * RSTRIDE + (size_t)(lane & 1) * 2];
      int spins = 0, sweep = 0;
      for (;;) {
        if (sweep < 6) {
          ld16_mall(ap, ra, rb);                 // fast path: single 16B load
        } else {
          ra = __hip_atomic_load(ap + 0, __ATOMIC_RELAXED, __HIP_MEMORY_SCOPE_AGENT);
          rb = __hip_atomic_load(ap + 1, __ATOMIC_RELAXED, __HIP_MEMORY_SCOPE_AGENT);
        }
        ++sweep;
        bool ok = (((unsigned)(ra >> TAG_SHIFT) == tag) &&
                   ((unsigned)(rb >> TAG_SHIFT) == tag));
        if (__all((int)ok)) break;
        ++spins;
        if (spins > (1 << 11)) break;            // bounded: clamped result, never hangs
        if ((spins & 63) == 0 && lane == 0) {    // heal via PROVEN atomic stores
          #pragma unroll
          for (int q = 0; q < 4; ++q)
            __hip_atomic_store(&bank[(size_t)wg * RSTRIDE + q], rc[q],
                               __ATOMIC_RELAXED, __HIP_MEMORY_SCOPE_AGENT);
        }
        if (spins > 512) __builtin_amdgcn_s_sleep(1);
      }
      // global top-4: each lane contributes its desc pair padded to a 4-list
      unsigned long long k1 = ra & KEY_MASK;
      unsigned long long k2 = rb & KEY_MASK;
      unsigned long long k3 = 0ull, k4 = 0ull;
      #pragma unroll
      for (int off = 32; off >= 1; off >>= 1) {
        unsigned long long o1 = __shfl_xor(k1, off);
        unsigned long long o2 = __shfl_xor(k2, off);
        unsigned long long o3 = __shfl_xor(k3, off);
        unsigned long long o4 = __shfl_xor(k4, off);
        merge4(k1, k2, k3, k4, o1, o2, o3, o4);
      }
      if (lane == 0) { lg[0] = k1; lg[1] = k2; lg[2] = k3; lg[3] = k4; }
    }
    __syncthreads();                       // B2
    unsigned long long g1 = lg[0], g2 = lg[1], g3 = lg[2], g4 = lg[3];
    ++c;

    int i1 = (int)(0x1FFFFu ^ (unsigned)(g1 & IDX_MASK));
    int i2 = (int)(0x1FFFFu ^ (unsigned)(g2 & IDX_MASK));
    int i3 = (int)(0x1FFFFu ^ (unsigned)(g3 & IDX_MASK));
    int i4 = (int)(0x1FFFFu ^ (unsigned)(g4 & IDX_MASK));
    if (i1 >= NPTS) i1 = 0;                // safety: never OOB
    if (i2 >= NPTS) i2 = 0;
    if (i3 >= NPTS) i3 = 0;
    if (i4 >= NPTS) i4 = 0;
    float v2 = __uint_as_float((unsigned)(g2 >> 17));
    float v3 = __uint_as_float((unsigned)(g3 >> 17));
    float v4 = __uint_as_float((unsigned)(g4 >> 17));

    // emit idx1
    if (wg == 0 && tid == 0) cross_inds[b * KFPS + t] = i1;
    ++t; w = i1;
    if (t >= KFPS) break;

    float e0x = pb[3 * i1 + 0], e0y = pb[3 * i1 + 1], e0z = pb[3 * i1 + 2];

    // ---- chain step 2 ----
    {
      float cx = pb[3 * i2 + 0], cy = pb[3 * i2 + 1], cz = pb[3 * i2 + 2];
      float dx = __fsub_rn(cx, e0x), dy = __fsub_rn(cy, e0y), dz = __fsub_rn(cz, e0z);
      float d2 = __fadd_rn(__fadd_rn(__fmul_rn(dx, dx), __fmul_rn(dy, dy)), __fmul_rn(dz, dz));
      if (!((v2 > 0.f) && (d2 >= v2) && (i2 != i1))) continue;
      FOLD(e0x, e0y, e0z);                 // fold e0 = i1
      if (wg == 0 && tid == 0) cross_inds[b * KFPS + t] = i2;
      ++t; w = i2;
      if (t >= KFPS) break;
    }
    float e1x = pb[3 * i2 + 0], e1y = pb[3 * i2 + 1], e1z = pb[3 * i2 + 2];

    // ---- chain step 3 ----
    {
      float cx = pb[3 * i3 + 0], cy = pb[3 * i3 + 1], cz = pb[3 * i3 + 2];
      float ax = __fsub_rn(cx, e0x), ay = __fsub_rn(cy, e0y), az = __fsub_rn(cz, e0z);
      float da = __fadd_rn(__fadd_rn(__fmul_rn(ax, ax), __fmul_rn(ay, ay)), __fmul_rn(az, az));
      float bx = __fsub_rn(cx, e1x), by = __fsub_rn(cy, e1y), bz = __fsub_rn(cz, e1z);
      float db = __fadd_rn(__fadd_rn(__fmul_rn(bx, bx), __fmul_rn(by, by)), __fmul_rn(bz, bz));
      if (!((v3 > 0.f) && (da >= v3) && (db >= v3))) continue;
      FOLD(e1x, e1y, e1z);                 // fold e1 = i2
      if (wg == 0 && tid == 0) cross_inds[b * KFPS + t] = i3;
      ++t; w = i3;
      if (t >= KFPS) break;
    }
    float e2x = pb[3 * i3 + 0], e2y = pb[3 * i3 + 1], e2z = pb[3 * i3 + 2];

    // ---- chain step 4 ----
    {
      float cx = pb[3 * i4 + 0], cy = pb[3 * i4 + 1], cz = pb[3 * i4 + 2];
      float ax = __fsub_rn(cx, e0x), ay = __fsub_rn(cy, e0y), az = __fsub_rn(cz, e0z);
      float da = __fadd_rn(__fadd_rn(__fmul_rn(ax, ax), __fmul_rn(ay, ay)), __fmul_rn(az, az));
      float bx = __fsub_rn(cx, e1x), by = __fsub_rn(cy, e1y), bz = __fsub_rn(cz, e1z);
      float db = __fadd_rn(__fadd_rn(__fmul_rn(bx, bx), __fmul_rn(by, by)), __fmul_rn(bz, bz));
      float gx = __fsub_rn(cx, e2x), gy = __fsub_rn(cy, e2y), gz = __fsub_rn(cz, e2z);
      float dg = __fadd_rn(__fadd_rn(__fmul_rn(gx, gx), __fmul_rn(gy, gy)), __fmul_rn(gz, gz));
      if (!((v4 > 0.f) && (da >= v4) && (db >= v4) && (dg >= v4))) continue;
      FOLD(e2x, e2y, e2z);                 // fold e2 = i3
      if (wg == 0 && tid == 0) cross_inds[b * KFPS + t] = i4;
      ++t; w = i4;
    }
  }
  #undef FOLD
}

// ============================================================
// Kernel 4: gathers (feats_sel, pts_sel, cross_features)
// ============================================================
#define GF4 ((NB * (KTOP + KFPS)) * (ND / 4))   // 589824 float4 gathers
#define GPTS (NB * KTOP * 3)                    // 6144

__global__ void k_gather(const float* __restrict__ pts,
                         const float* __restrict__ feat,
                         const int* __restrict__ sorti,
                         const int* __restrict__ crossi,
                         float* __restrict__ out) {
  int id = blockIdx.x * 256 + threadIdx.x;
  if (id < GF4) {
    int row = id >> 5, c4 = id & 31;
    int b, s; float* dst;
    if (row < NB * KTOP) {
      b = row >> 8;
      s = sorti[row];
      dst = out + OUT_FEATS + (size_t)row * ND;
    } else {
      int r2 = row - NB * KTOP;
      b = r2 >> 11;
      s = crossi[r2];
      dst = out + OUT_CROSS + (size_t)r2 * ND;
    }
    if (s < 0 || s >= NPTS) s = 0;
    float4 v = ((const float4*)(feat + ((size_t)b * NPTS + (size_t)s) * ND))[c4];
    ((float4*)dst)[c4] = v;
  } else if (id < GF4 + GPTS) {
    int q = id - GF4;
    int row = q / 3, d = q - row * 3;
    int b = row >> 8;
    int s = sorti[row];
    if (s < 0 || s >= NPTS) s = 0;
    out[OUT_PTS + q] = pts[((size_t)b * NPTS + (size_t)s) * 3 + d];
  }
}

// ============================================================
extern "C" void kernel_launch(void* const* d_in, const int* in_sizes, int n_in,
                              void* d_out, int out_size, void* d_ws, size_t ws_size,
                              hipStream_t stream) {
  const float* cent = (const float*)d_in[0];
  const float* cls  = (const float*)d_in[1];
  const float* pts  = (const float*)d_in[2];
  const float* feat = (const float*)d_in[3];
  float* out = (float*)d_out;

  unsigned long long* partials = (unsigned long long*)(out + OUT_PART);
  int* cross_ws = (int*)((char*)d_ws + WS_CROSS);
  int* sorti_ws = (int*)((char*)d_ws + WS_SORTI);
  float* scores = out + OUT_SCORES;

  hipLaunchKernelGGL(k_init, dim3((PART_U64 + 255) / 256), dim3(256), 0, stream,
                     partials);
  hipLaunchKernelGGL(k_scores, dim3((NB * NPTS + 255) / 256), dim3(256), 0, stream,
                     cent, cls, scores);
  hipLaunchKernelGGL(k_topk, dim3(NB), dim3(1024), 0, stream,
                     scores, sorti_ws, out + OUT_INDS);
  hipLaunchKernelGGL(k_fps, dim3(NB * FWGS), dim3(FTHR), 0, stream,
                     pts, partials, cross_ws);
  int gtot = GF4 + GPTS;
  hipLaunchKernelGGL(k_gather, dim3((gtot + 255) / 256), dim3(256), 0, stream,
                     pts, feat, sorti_ws, cross_ws, out);
}

// Round 17
// 3472.799 us; speedup vs baseline: 1.2383x; 1.1067x over previous
//
#include <hip/hip_runtime.h>
#include <math.h>

// ---------------- problem constants ----------------
#define NB    8
#define NPTS  100000
#define NCLS  18
#define ND    128
#define KFPS  2048
#define KTOP  256

// ---------------- FPS config ----------------
#define FWGS       32                 // workgroups per batch
#define FTHR       256                // threads per WG
#define FBTHREADS  (FWGS*FTHR)        // 8192 threads per batch
#define PPT        13                 // points per thread (13*8192 >= 100000)
#define NSLOT      32                 // one slot (2 records, 16B) per WG per batch
#define RSTRIDE    64                 // u64s per slot (512 B) -> MALL slice spread
#define TAG_SHIFT  49
#define KEY_MASK   ((1ull<<TAG_SHIFT)-1)
#define IDX_MASK   0x1FFFFull
#define INVALID_REC (~0ull)           // tag 0x7FFF: never matches live tags

// per-batch u64 region: 2 banks x 32 slots x 64 u64-stride
#define BANK_U64   (NSLOT * RSTRIDE)            // 2048
#define B_TOTAL    (2 * BANK_U64)               // 4096
#define PART_U64   (NB * B_TOTAL)               // 32768 u64 = 256 KB

static_assert(PPT * FBTHREADS >= NPTS, "coverage");

// ---------------- out layout (float elements), total 2367488 ----------------
#define OUT_PTS    0          // 8*256*3    = 6144
#define OUT_FEATS  6144       // 8*256*128  = 262144
#define OUT_INDS   268288     // 8*256      = 2048
#define OUT_CROSS  270336     // 8*2048*128 = 2097152
// scratch INSIDE region 3 (overwritten by k_gather at the end):
#define OUT_SCORES OUT_CROSS              // 800000 floats
#define OUT_PART   (OUT_CROSS + 800000)   // 8B-aligned
static_assert((OUT_PART % 2) == 0, "u64 alignment");
static_assert(OUT_PART + PART_U64 * 2 <= OUT_CROSS + 2097152, "fits in region 3");

// ---------------- ws layout (bytes) — proven-safe 90112 ----------------
#define WS_CROSS    16384                   // NB*KFPS*4 = 65536
#define WS_SORTI    (16384+65536)           // NB*KTOP*4 = 8192   (end 90112)

typedef unsigned int uint32x4 __attribute__((ext_vector_type(4)));

// one 16B MALL-coherent load -> two u64 records, single round trip.
// Validated bit-exact r15/r16. Tag-in-u64 self-verifies freshness.
__device__ __forceinline__ void ld16_mall(const unsigned long long* p,
                                          unsigned long long& lo,
                                          unsigned long long& hi) {
  uint32x4 v;
  asm volatile("global_load_dwordx4 %0, %1, off sc0 sc1\n\ts_waitcnt vmcnt(0)"
               : "=v"(v) : "v"((unsigned long long)p) : "memory");
  lo = ((unsigned long long)v.y << 32) | (unsigned long long)v.x;
  hi = ((unsigned long long)v.w << 32) | (unsigned long long)v.z;
}
// one 16B store publishing two tagged records in a single transaction.
// Validated r16. Partial visibility -> tag mismatch -> retry (safe).
__device__ __forceinline__ void st16_mall(unsigned long long* p,
                                          unsigned long long lo,
                                          unsigned long long hi) {
  uint32x4 v;
  v.x = (unsigned)lo; v.y = (unsigned)(lo >> 32);
  v.z = (unsigned)hi; v.w = (unsigned)(hi >> 32);
  asm volatile("global_store_dwordx4 %0, %1, off sc0 sc1"
               :: "v"((unsigned long long)p), "v"(v) : "memory");
}

// ============================================================
// Kernel 0: init record slots (runs before k_fps every call)
// ============================================================
__global__ void k_init(unsigned long long* __restrict__ partials) {
  int id = blockIdx.x * 256 + threadIdx.x;
  if (id < PART_U64)
    __hip_atomic_store(&partials[id], INVALID_REC,
                       __ATOMIC_RELAXED, __HIP_MEMORY_SCOPE_AGENT);
}

// ============================================================
// Kernel 1: max_scores = sigmoid(max_c cls) * sigmoid(centerness)
// ============================================================
__global__ void k_scores(const float* __restrict__ cent,
                         const float* __restrict__ cls,
                         float* __restrict__ scores) {
  int gid = blockIdx.x * blockDim.x + threadIdx.x;
  if (gid >= NB * NPTS) return;
  const float* c = cls + (size_t)gid * NCLS;
  float m = c[0];
  #pragma unroll
  for (int i = 1; i < NCLS; ++i) m = fmaxf(m, c[i]);
  double sm = 1.0 / (1.0 + exp(-(double)m));
  double sc = 1.0 / (1.0 + exp(-(double)cent[gid]));
  scores[gid] = __fmul_rn((float)sm, (float)sc);
}

// ============================================================
// Kernel 2: per-batch exact top-256 (value desc, idx asc), output sorted idx
// ============================================================
__global__ __launch_bounds__(1024) void k_topk(const float* __restrict__ scores,
                                               int* __restrict__ sorti_ws,
                                               float* __restrict__ out_inds) {
  __shared__ unsigned hist[2048];
  __shared__ int candG[256];
  __shared__ int candE[512];
  __shared__ unsigned s_cg, s_ce, s_bin, s_rank;

  int b = blockIdx.x;
  int tid = threadIdx.x;
  const float* sb = scores + (size_t)b * NPTS;

  unsigned prefix = 0, pmask = 0;
  int r = KTOP;
  for (int pass = 0; pass < 3; ++pass) {
    int shift = (pass == 0) ? 21 : (pass == 1) ? 10 : 0;
    int bins  = (pass < 2) ? 2048 : 1024;
    for (int i = tid; i < bins; i += 1024) hist[i] = 0;
    __syncthreads();
    for (int n = tid; n < NPTS; n += 1024) {
      unsigned k = __float_as_uint(sb[n]);
      if ((k & pmask) == prefix) atomicAdd(&hist[(k >> shift) & (bins - 1)], 1u);
    }
    __syncthreads();
    if (tid == 0) {
      unsigned c = 0; int bin = bins - 1;
      for (; bin > 0; --bin) { unsigned h = hist[bin]; if (c + h >= (unsigned)r) break; c += h; }
      s_bin = (unsigned)bin; s_rank = (unsigned)r - c;
    }
    __syncthreads();
    prefix |= s_bin << shift;
    pmask  |= (unsigned)(bins - 1) << shift;
    r = (int)s_rank;
    __syncthreads();
  }
  unsigned T = prefix;
  int need = r;
  int nG = KTOP - need;

  if (tid == 0) { s_cg = 0; s_ce = 0; }
  __syncthreads();
  for (int n = tid; n < NPTS; n += 1024) {
    unsigned k = __float_as_uint(sb[n]);
    if (k > T)       { unsigned p = atomicAdd(&s_cg, 1u); if (p < 256) candG[p] = n; }
    else if (k == T) { unsigned p = atomicAdd(&s_ce, 1u); if (p < 512) candE[p] = n; }
  }
  __syncthreads();
  unsigned ce = s_ce;
  for (int i = tid; i < 512; i += 1024) if (i >= (int)ce) candE[i] = 0x7FFFFFFF;
  __syncthreads();
  for (int k2 = 2; k2 <= 512; k2 <<= 1)
    for (int j = k2 >> 1; j >= 1; j >>= 1) {
      if (tid < 512) {
        int i = tid, p = i ^ j;
        if (p > i) {
          int a = candE[i], bb = candE[p];
          bool up = ((i & k2) == 0);
          if ((a > bb) == up) { candE[i] = bb; candE[p] = a; }
        }
      }
      __syncthreads();
    }
  int* arr = (int*)hist;
  if (tid < KTOP) arr[tid] = (tid < nG) ? candG[tid] : candE[tid - nG];
  __syncthreads();
  for (int k2 = 2; k2 <= 256; k2 <<= 1)
    for (int j = k2 >> 1; j >= 1; j >>= 1) {
      if (tid < 256) {
        int i = tid, p = i ^ j;
        if (p > i) {
          int a = arr[i], bb = arr[p];
          bool up = ((i & k2) == 0);
          if ((a > bb) == up) { arr[i] = bb; arr[p] = a; }
        }
      }
      __syncthreads();
    }
  if (tid < KTOP) {
    sorti_ws[b * KTOP + tid] = arr[tid];
    out_inds[b * KTOP + tid] = (float)arr[tid];
  }
}

// ---- merge two descending-sorted key pairs from DISJOINT point sets ----
__device__ __forceinline__ void merge2(unsigned long long& b1, unsigned long long& b2,
                                       unsigned long long o1, unsigned long long o2) {
  if (o1 > b1) { unsigned long long t1 = b1; b1 = o1; b2 = (o2 > t1) ? o2 : t1; }
  else         { b2 = (o1 > b2) ? o1 : b2; }
}

// ============================================================
// Kernel 3: FPS, exact top-2 lookahead (r13-proven protocol) at the
// measured-minimal transaction count: publish = ONE 16B store (2 tagged
// records), poll = ONE 16B load per lane (lanes 0-31). Chain step 2
// identical to r13. Heal/fallback via proven per-record atomic ops.
// Tag = consensus counter + 1; ping-pong banks; bounded spins; clamps.
// ============================================================
__global__ __launch_bounds__(FTHR, 1) void k_fps(const float* __restrict__ points,
                                                 unsigned long long* __restrict__ partials,
                                                 int* __restrict__ cross_inds) {
  int b    = blockIdx.x & 7;
  int wg   = blockIdx.x >> 3;    // 0..31
  int tid  = threadIdx.x;
  int lane = tid & 63;
  int wave = tid >> 6;           // 0..3
  int gthr = wg * FTHR + tid;

  __shared__ unsigned long long lred[4][2];
  __shared__ unsigned long long lg[2];

  const float* pb = points + (size_t)b * NPTS * 3;
  unsigned long long* base = partials + (size_t)b * B_TOTAL;

  float px[PPT], py[PPT], pz[PPT], dd[PPT];
  #pragma unroll
  for (int i = 0; i < PPT; ++i) {
    int n = gthr + i * FBTHREADS;
    bool v = (n < NPTS);
    px[i] = v ? pb[3 * n + 0] : 0.f;
    py[i] = v ? pb[3 * n + 1] : 0.f;
    pz[i] = v ? pb[3 * n + 2] : 0.f;
    dd[i] = 1e10f;
  }
  if (wg == 0 && tid == 0) cross_inds[b * KFPS] = 0;

  #define FOLD(fx, fy, fz) do {                                               \
    _Pragma("unroll")                                                         \
    for (int i_ = 0; i_ < PPT; ++i_) {                                        \
      float dx_ = __fsub_rn(px[i_], (fx));                                    \
      float dy_ = __fsub_rn(py[i_], (fy));                                    \
      float dz_ = __fsub_rn(pz[i_], (fz));                                    \
      float s_  = __fadd_rn(__fadd_rn(__fmul_rn(dx_, dx_), __fmul_rn(dy_, dy_)), \
                            __fmul_rn(dz_, dz_));                             \
      dd[i_] = fminf(dd[i_], s_);                                             \
    }                                                                         \
  } while (0)

  int w = 0;          // emitted, to fold at next update pass
  int t = 1;          // next emission slot
  int c = 0;          // consensus counter
  while (t < KFPS) {
    float wx = pb[3 * w + 0];
    float wy = pb[3 * w + 1];
    float wz = pb[3 * w + 2];

    // update pass + per-thread top-2 (packed (val,~idx) keys, desc b1,b2)
    unsigned long long b1 = 0ull, b2 = 0ull;
    #pragma unroll
    for (int i = 0; i < PPT; ++i) {
      int n = gthr + i * FBTHREADS;
      float dx = __fsub_rn(px[i], wx);
      float dy = __fsub_rn(py[i], wy);
      float dz = __fsub_rn(pz[i], wz);
      float s  = __fadd_rn(__fadd_rn(__fmul_rn(dx, dx), __fmul_rn(dy, dy)), __fmul_rn(dz, dz));
      float nd = fminf(dd[i], s);
      dd[i] = nd;
      if (n < NPTS) {
        unsigned long long k = ((unsigned long long)__float_as_uint(nd) << 17) |
                               (unsigned long long)(0x1FFFFu ^ (unsigned)n);
        if (k > b1) { b2 = b1; b1 = k; } else if (k > b2) { b2 = k; }
      }
    }
    // wave butterfly top-2
    #pragma unroll
    for (int off = 32; off >= 1; off >>= 1) {
      unsigned long long o1 = __shfl_xor(b1, off);
      unsigned long long o2 = __shfl_xor(b2, off);
      merge2(b1, b2, o1, o2);
    }
    if (lane == 0) { lred[wave][0] = b1; lred[wave][1] = b2; }
    __syncthreads();                       // B1

    unsigned tag = (unsigned)c + 1u;
    unsigned long long* bank = base + (size_t)(c & 1) * BANK_U64;
    if (wave == 0) {
      unsigned long long rec1 = 0, rec2 = 0;
      if (lane == 0) {
        unsigned long long m1 = lred[0][0], m2 = lred[0][1];
        merge2(m1, m2, lred[1][0], lred[1][1]);
        merge2(m1, m2, lred[2][0], lred[2][1]);
        merge2(m1, m2, lred[3][0], lred[3][1]);
        rec1 = ((unsigned long long)tag << TAG_SHIFT) | m1;
        rec2 = ((unsigned long long)tag << TAG_SHIFT) | m2;
        st16_mall(&bank[(size_t)wg * RSTRIDE], rec1, rec2);  // ONE transaction
      }
      // poll: lanes 0..31, ONE 16B load per lane covering both records
      unsigned long long r1 = 0, r2 = 0;
      unsigned long long* ap = &bank[(size_t)(lane & 31) * RSTRIDE];
      int spins = 0, sweep = 0;
      for (;;) {
        if (lane < 32) {
          if (sweep < 6) {
            ld16_mall(ap, r1, r2);               // fast path
          } else {
            r1 = __hip_atomic_load(ap + 0, __ATOMIC_RELAXED, __HIP_MEMORY_SCOPE_AGENT);
            r2 = __hip_atomic_load(ap + 1, __ATOMIC_RELAXED, __HIP_MEMORY_SCOPE_AGENT);
          }
        }
        ++sweep;
        bool ok = (lane >= 32) || (((unsigned)(r1 >> TAG_SHIFT) == tag) &&
                                   ((unsigned)(r2 >> TAG_SHIFT) == tag));
        if (__all((int)ok)) break;
        ++spins;
        if (spins > (1 << 11)) break;            // bounded: clamped result, never hangs
        if ((spins & 255) == 0 && lane == 0) {   // heal via PROVEN atomic stores
          __hip_atomic_store(&bank[(size_t)wg * RSTRIDE + 0], rec1,
                             __ATOMIC_RELAXED, __HIP_MEMORY_SCOPE_AGENT);
          __hip_atomic_store(&bank[(size_t)wg * RSTRIDE + 1], rec2,
                             __ATOMIC_RELAXED, __HIP_MEMORY_SCOPE_AGENT);
        }
        if (spins > 512) __builtin_amdgcn_s_sleep(1);
      }
      unsigned long long k1 = (lane < 32) ? (r1 & KEY_MASK) : 0ull;
      unsigned long long k2 = (lane < 32) ? (r2 & KEY_MASK) : 0ull;
      #pragma unroll
      for (int off = 32; off >= 1; off >>= 1) {
        unsigned long long o1 = __shfl_xor(k1, off);
        unsigned long long o2 = __shfl_xor(k2, off);
        merge2(k1, k2, o1, o2);
      }
      if (lane == 0) { lg[0] = k1; lg[1] = k2; }
    }
    __syncthreads();                       // B2
    unsigned long long g1 = lg[0], g2 = lg[1];
    ++c;

    int i1 = (int)(0x1FFFFu ^ (unsigned)(g1 & IDX_MASK));
    int i2 = (int)(0x1FFFFu ^ (unsigned)(g2 & IDX_MASK));
    if (i1 >= NPTS) i1 = 0;                // safety: never OOB
    if (i2 >= NPTS) i2 = 0;
    float v2 = __uint_as_float((unsigned)(g2 >> 17));

    // emit idx1
    if (wg == 0 && tid == 0) cross_inds[b * KFPS + t] = i1;
    ++t; w = i1;
    if (t >= KFPS) break;

    // exact speculation check (uniform across all threads and WGs)
    float e0x = pb[3 * i1 + 0], e0y = pb[3 * i1 + 1], e0z = pb[3 * i1 + 2];
    float cx = pb[3 * i2 + 0], cy = pb[3 * i2 + 1], cz = pb[3 * i2 + 2];
    float dx = __fsub_rn(cx, e0x), dy = __fsub_rn(cy, e0y), dz = __fsub_rn(cz, e0z);
    float d2 = __fadd_rn(__fadd_rn(__fmul_rn(dx, dx), __fmul_rn(dy, dy)), __fmul_rn(dz, dz));
    if ((v2 > 0.f) && (d2 >= v2) && (i2 != i1)) {
      FOLD(e0x, e0y, e0z);                 // fold e0 = i1 (no consensus needed)
      if (wg == 0 && tid == 0) cross_inds[b * KFPS + t] = i2;
      ++t; w = i2;
    }
  }
  #undef FOLD
}

// ============================================================
// Kernel 4: gathers (feats_sel, pts_sel, cross_features)
// ============================================================
#define GF4 ((NB * (KTOP + KFPS)) * (ND / 4))   // 589824 float4 gathers
#define GPTS (NB * KTOP * 3)                    // 6144

__global__ void k_gather(const float* __restrict__ pts,
                         const float* __restrict__ feat,
                         const int* __restrict__ sorti,
                         const int* __restrict__ crossi,
                         float* __restrict__ out) {
  int id = blockIdx.x * 256 + threadIdx.x;
  if (id < GF4) {
    int row = id >> 5, c4 = id & 31;
    int b, s; float* dst;
    if (row < NB * KTOP) {
      b = row >> 8;
      s = sorti[row];
      dst = out + OUT_FEATS + (size_t)row * ND;
    } else {
      int r2 = row - NB * KTOP;
      b = r2 >> 11;
      s = crossi[r2];
      dst = out + OUT_CROSS + (size_t)r2 * ND;
    }
    if (s < 0 || s >= NPTS) s = 0;
    float4 v = ((const float4*)(feat + ((size_t)b * NPTS + (size_t)s) * ND))[c4];
    ((float4*)dst)[c4] = v;
  } else if (id < GF4 + GPTS) {
    int q = id - GF4;
    int row = q / 3, d = q - row * 3;
    int b = row >> 8;
    int s = sorti[row];
    if (s < 0 || s >= NPTS) s = 0;
    out[OUT_PTS + q] = pts[((size_t)b * NPTS + (size_t)s) * 3 + d];
  }
}

// ============================================================
extern "C" void kernel_launch(void* const* d_in, const int* in_sizes, int n_in,
                              void* d_out, int out_size, void* d_ws, size_t ws_size,
                              hipStream_t stream) {
  const float* cent = (const float*)d_in[0];
  const float* cls  = (const float*)d_in[1];
  const float* pts  = (const float*)d_in[2];
  const float* feat = (const float*)d_in[3];
  float* out = (float*)d_out;

  unsigned long long* partials = (unsigned long long*)(out + OUT_PART);
  int* cross_ws = (int*)((char*)d_ws + WS_CROSS);
  int* sorti_ws = (int*)((char*)d_ws + WS_SORTI);
  float* scores = out + OUT_SCORES;

  hipLaunchKernelGGL(k_init, dim3((PART_U64 + 255) / 256), dim3(256), 0, stream,
                     partials);
  hipLaunchKernelGGL(k_scores, dim3((NB * NPTS + 255) / 256), dim3(256), 0, stream,
                     cent, cls, scores);
  hipLaunchKernelGGL(k_topk, dim3(NB), dim3(1024), 0, stream,
                     scores, sorti_ws, out + OUT_INDS);
  hipLaunchKernelGGL(k_fps, dim3(NB * FWGS), dim3(FTHR), 0, stream,
                     pts, partials, cross_ws);
  int gtot = GF4 + GPTS;
  hipLaunchKernelGGL(k_gather, dim3((gtot + 255) / 256), dim3(256), 0, stream,
                     pts, feat, sorti_ws, cross_ws, out);
}